// Round 3
// baseline (155.899 us; speedup 1.0000x reference)
//
#include <hip/hip_runtime.h>

#define RADIUS 8
#define N 512
#define TR 32                    // output rows per strip
#define SPB 4                    // strips per block (register-carry ring)
#define LSTRIDE (N + 1)          // LDS stride 513 ≡ 1 (mod 32) → conflict-free
#define NXCD 8
#define NWG (8 * 32 * (N / (TR * SPB)))   // 256 images * 4 groups = 1024 blocks

__global__ __launch_bounds__(512, 4)
void box_kernel(const float* __restrict__ in, float* __restrict__ out) {
    __shared__ float tile[TR * LSTRIDE];   // 64.1 KiB → 2 blocks/CU

    // XCD-aware swizzle: adjacent groups (sharing boundary halo) → same XCD L2.
    const int bid = blockIdx.x;
    const int blk = (bid % NXCD) * (NWG / NXCD) + bid / NXCD;

    const int img   = blk >> 2;            // 4 groups per image
    const int grp   = blk & 3;
    const int rbase = grp * (TR * SPB);    // first output row of this block
    const float* __restrict__ ibase = in  + (size_t)img * N * N;
    float* __restrict__       obase = out + (size_t)img * N * N;
    const int c = threadIdx.x;             // column 0..511

    // Circular register window: slot (b_s + k) % 48 holds window row k of strip s,
    // where b_s = (32*s) % 48. Carry between strips costs zero moves.
    float x[48];
#pragma unroll
    for (int k = 0; k < 48; ++k) {         // strip 0 window: rows rbase-8 .. rbase+39
        const int row = rbase + k - RADIUS;
        x[k] = (row >= 0 && row < N) ? ibase[(size_t)row * N + c] : 0.0f;
    }

    const int hrow = threadIdx.x & (TR - 1);   // phase-2 row 0..31
    const int seg  = threadIdx.x >> 5;         // phase-2 col segment 0..15
    const int c0   = seg * 32;

#pragma unroll
    for (int s = 0; s < SPB; ++s) {
        const int b  = (32 * s) % 48;      // compile-time after unroll
        const int r0 = rbase + s * TR;

        // ---- Phase 1: vertical 17-tap sliding sum from register ring ----
        float vs = 0.0f;
#pragma unroll
        for (int k = 0; k <= 2 * RADIUS; ++k) vs += x[(b + k) % 48];
#pragma unroll
        for (int i = 0; i < TR; ++i) {
            tile[i * LSTRIDE + c] = vs;
            if (i + 1 < TR) vs += x[(b + i + 2 * RADIUS + 1) % 48] - x[(b + i) % 48];
        }
        __syncthreads();

        // ---- Prefetch next strip's 32 fresh rows (overlaps phase-2 compute).
        // Fresh rows r0+40 .. r0+71 land in slots (b+k)%48 (dead after phase 1).
        if (s + 1 < SPB) {
#pragma unroll
            for (int k = 0; k < 32; ++k) {
                const int row = r0 + TR + RADIUS + k;      // always >= 0
                x[(b + k) % 48] = (row < N) ? ibase[(size_t)row * N + c] : 0.0f;
            }
        }

        // ---- Phase 2: horizontal 17-tap sliding sum from LDS tile ----
        const float* trow = &tile[hrow * LSTRIDE];
        float hs = 0.0f;
#pragma unroll
        for (int k = -RADIUS; k <= RADIUS; ++k) {
            const int col = c0 + k;
            if (col >= 0 && col < N) hs += trow[col];
        }
        float h[32];
#pragma unroll
        for (int j = 0; j < 32; ++j) {
            h[j] = hs;
            const int ac = c0 + j + 1 + RADIUS;
            const int sc = c0 + j - RADIUS;
            const float a  = (ac < N) ? trow[ac] : 0.0f;
            const float sb = (sc >= 0) ? trow[sc] : 0.0f;
            hs += a - sb;
        }

        // ---- Direct float4 stores (skip LDS round-trip; L2 merges into full lines)
        float* orow = obase + (size_t)(r0 + hrow) * N + c0;
#pragma unroll
        for (int g = 0; g < 8; ++g) {
            *reinterpret_cast<float4*>(orow + 4 * g) =
                make_float4(h[4 * g], h[4 * g + 1], h[4 * g + 2], h[4 * g + 3]);
        }

        if (s + 1 < SPB) __syncthreads();  // tile reads done before next overwrite
    }
}

extern "C" void kernel_launch(void* const* d_in, const int* in_sizes, int n_in,
                              void* d_out, int out_size, void* d_ws, size_t ws_size,
                              hipStream_t stream) {
    const float* in = (const float*)d_in[0];
    float* out = (float*)d_out;
    dim3 grid(NWG);               // 1024 blocks
    dim3 block(512);
    hipLaunchKernelGGL(box_kernel, grid, block, 0, stream, in, out);
}